// Round 12
// baseline (269.300 us; speedup 1.0000x reference)
//
#include <hip/hip_runtime.h>
#include <hip/hip_bf16.h>
#include <cstdint>

#define DIM 1536
#define NHEADS 12
#define HD 128
#define SEQ 3840
#define SCL2F 0.1275365308119098f   /* (1/sqrt(128)) * log2(e) */
#define THRRAW 90.50966799187809f   /* 8 nats / (1/sqrt(128))  */

typedef float f32x4 __attribute__((ext_vector_type(4)));
typedef __bf16 bf16x8 __attribute__((ext_vector_type(8)));
typedef __bf16 bf16x4 __attribute__((ext_vector_type(4)));
typedef __bf16 bf16x2 __attribute__((ext_vector_type(2)));
typedef unsigned int u32;
typedef u32 u32x4 __attribute__((ext_vector_type(4)));

#define GLLD(g, l) __builtin_amdgcn_global_load_lds( \
    (const __attribute__((address_space(1))) void*)(g), \
    (__attribute__((address_space(3))) void*)(l), 16, 0, 0)

// ---------------- fp32 -> bf16 convert, 5 tensors in one launch ----------------
__global__ __launch_bounds__(256) void cvt_bf16_5(
    const float* __restrict__ s0, const float* __restrict__ s1, const float* __restrict__ s2,
    const float* __restrict__ s3, const float* __restrict__ s4,
    __bf16* __restrict__ d0, __bf16* __restrict__ d1, __bf16* __restrict__ d2,
    __bf16* __restrict__ d3, __bf16* __restrict__ d4,
    int n4_0, int n4_w) {
    const float* src; __bf16* dst; int n4;
    switch (blockIdx.y) {
        case 0: src = s0; dst = d0; n4 = n4_0; break;
        case 1: src = s1; dst = d1; n4 = n4_w; break;
        case 2: src = s2; dst = d2; n4 = n4_w; break;
        case 3: src = s3; dst = d3; n4 = n4_w; break;
        default: src = s4; dst = d4; n4 = n4_w; break;
    }
    int i = blockIdx.x * 256 + threadIdx.x;
    if (i < n4) {
        f32x4 v = ((const f32x4*)src)[i];
        bf16x4 o;
        o[0] = (__bf16)v[0]; o[1] = (__bf16)v[1];
        o[2] = (__bf16)v[2]; o[3] = (__bf16)v[3];
        ((bf16x4*)dst)[i] = o;
    }
}

// ---------------- GEMM 256x128, BK=32, triple-buffer, counted vmcnt ----------
template <int OUTF32>
__global__ __launch_bounds__(256, 2) void gemm256(
    const __bf16* __restrict__ A,
    const __bf16* __restrict__ B0, const __bf16* __restrict__ B1, const __bf16* __restrict__ B2,
    const float* __restrict__ bias0, const float* __restrict__ bias1, const float* __restrict__ bias2,
    void* __restrict__ C0v, void* __restrict__ C1v, void* __restrict__ C2v,
    int N, int K) {
    // --- XCD-bijective remap (nwg % 8 may be != 0) ---
    const int orig = blockIdx.x;
    const int nwg = gridDim.x;
    const int qq_ = nwg >> 3, rr_ = nwg & 7;
    const int xcd = orig & 7, off = orig >> 3;
    const int wgid = (xcd < rr_ ? xcd * (qq_ + 1) : rr_ * (qq_ + 1) + (xcd - rr_) * qq_) + off;
    const int z = wgid / 180;
    const int rem = wgid - z * 180;
    const int by = rem / 12;       // m-block (y-major: same-A blocks contiguous)
    const int bx = rem - by * 12;  // n-block

    const __bf16* B = B0; const float* bias = bias0; void* Cv = C0v;
    if (z == 1) { B = B1; bias = bias1; Cv = C1v; }
    else if (z == 2) { B = B2; bias = bias2; Cv = C2v; }

    __shared__ __bf16 sA[3][256 * 32];   // 16KB x3
    __shared__ __bf16 sB[3][128 * 32];   // 8KB x3  -> 72KB total

    const int t = threadIdx.x;
    const int wid = t >> 6, lane = t & 63;
    const int lr = lane & 15, lg = lane >> 4;
    const int wr = (wid >> 1) * 128, wc = (wid & 1) * 64;

    const __bf16* pa = A + ((long long)by * 256 + (t >> 2)) * K + (t & 3) * 8;
    const __bf16* pb = B + ((long long)bx * 128 + (t >> 2)) * K + (t & 3) * 8;
    const int ldsbase = wid * 512;

    auto stage = [&](int kk, int bufi) {
#pragma unroll
        for (int r = 0; r < 4; r++)
            GLLD(pa + (long long)(r * 64) * K + kk, &sA[bufi][r * 2048 + ldsbase]);
#pragma unroll
        for (int r = 0; r < 2; r++)
            GLLD(pb + (long long)(r * 64) * K + kk, &sB[bufi][r * 2048 + ldsbase]);
    };

    f32x4 acc[8][4] = {};
    const int NT = K / 32;

    stage(0, 0);
    stage(32, 1);
    asm volatile("s_waitcnt vmcnt(6)" ::: "memory");
    __builtin_amdgcn_s_barrier();
    __builtin_amdgcn_sched_barrier(0);

    int c0 = 0, c2 = 2;
#pragma unroll 1
    for (int i = 0; i < NT; i++) {
        const __bf16* sAc = &sA[0][0] + c0 * (256 * 32);
        const __bf16* sBc = &sB[0][0] + c0 * (128 * 32);
        bf16x8 af[8], bfr[4];
#pragma unroll
        for (int mI = 0; mI < 8; mI++)
            af[mI] = *(const bf16x8*)(sAc + (wr + mI * 16 + lr) * 32 + lg * 8);
#pragma unroll
        for (int nI = 0; nI < 4; nI++)
            bfr[nI] = *(const bf16x8*)(sBc + (wc + nI * 16 + lr) * 32 + lg * 8);
        if (i + 2 < NT) stage((i + 2) * 32, c2);

        __builtin_amdgcn_s_setprio(1);
#pragma unroll
        for (int mI = 0; mI < 8; mI++) {
            acc[mI][0] = __builtin_amdgcn_mfma_f32_16x16x32_bf16(af[mI], bfr[0], acc[mI][0], 0, 0, 0);
            acc[mI][1] = __builtin_amdgcn_mfma_f32_16x16x32_bf16(af[mI], bfr[1], acc[mI][1], 0, 0, 0);
        }
        __builtin_amdgcn_s_setprio(0);
        __builtin_amdgcn_s_barrier();
        __builtin_amdgcn_s_setprio(1);
#pragma unroll
        for (int mI = 0; mI < 8; mI++) {
            acc[mI][2] = __builtin_amdgcn_mfma_f32_16x16x32_bf16(af[mI], bfr[2], acc[mI][2], 0, 0, 0);
            acc[mI][3] = __builtin_amdgcn_mfma_f32_16x16x32_bf16(af[mI], bfr[3], acc[mI][3], 0, 0, 0);
        }
        __builtin_amdgcn_s_setprio(0);

        if (i + 2 < NT) asm volatile("s_waitcnt vmcnt(6)" ::: "memory");
        else            asm volatile("s_waitcnt vmcnt(0)" ::: "memory");
        __builtin_amdgcn_s_barrier();
        __builtin_amdgcn_sched_barrier(0);
        c0 = (c0 == 2) ? 0 : c0 + 1;
        c2 = (c2 == 2) ? 0 : c2 + 1;
    }

    const int cb = bx * 128 + wc;
    const int rb_ = by * 256 + wr;
#pragma unroll
    for (int nI = 0; nI < 4; nI++) {
        int col = cb + nI * 16 + lr;
        float bv = bias[col];
#pragma unroll
        for (int mI = 0; mI < 8; mI++) {
            int row0 = rb_ + mI * 16 + lg * 4;
#pragma unroll
            for (int r = 0; r < 4; r++) {
                float v = acc[mI][nI][r] + bv;
                if (OUTF32) ((float*)Cv)[(long long)(row0 + r) * N + col] = v;
                else ((__bf16*)Cv)[(long long)(row0 + r) * N + col] = (__bf16)v;
            }
        }
    }
}

// ------ fused post-QKV pass: y=0 norm(q), y=1 norm(k), y=2 V-transpose -------
__global__ __launch_bounds__(256) void norm_tr(
    const __bf16* __restrict__ qpre, const __bf16* __restrict__ kpre,
    const float* __restrict__ gq, const float* __restrict__ gk,
    const float* __restrict__ fcos, const float* __restrict__ fsin,
    __bf16* __restrict__ Qb, __bf16* __restrict__ Kb,
    const __bf16* __restrict__ vpre, __bf16* __restrict__ Vtb) {
    __shared__ __bf16 tile[64][68];
    __shared__ float red[4];
    const int t = threadIdx.x;

    if (blockIdx.y == 2) {
        // ---- transpose [SEQ][DIM] -> [DIM][SEQ] with kv-slot permute ----
        const int bxx = blockIdx.x;
        if (bxx >= (SEQ / 64) * (DIM / 64)) return;
        const int sb = (bxx % (SEQ / 64)) * 64, cb = (bxx / (SEQ / 64)) * 64;
        const int tx = t & 15, ty = t >> 4;
#pragma unroll
        for (int i = 0; i < 4; i++) {
            int r = ty + i * 16;
            bf16x4 v = *(const bf16x4*)(vpre + (size_t)(sb + r) * DIM + cb + tx * 4);
            *(bf16x4*)&tile[r][tx * 4] = v;
        }
        __syncthreads();
        int s0 = sb + tx * 4;
        int j = (s0 >> 2) & 7;
        int u = (j < 4) ? (j << 1) : ((j << 1) - 7);
        int sp = (s0 & ~31) + (u << 2);
#pragma unroll
        for (int i = 0; i < 4; i++) {
            int c = ty + i * 16;
            bf16x4 v;
            v[0] = tile[tx * 4 + 0][c]; v[1] = tile[tx * 4 + 1][c];
            v[2] = tile[tx * 4 + 2][c]; v[3] = tile[tx * 4 + 3][c];
            *(bf16x4*)(Vtb + (size_t)(cb + c) * SEQ + sp) = v;
        }
        return;
    }

    // ---- RMSNorm + RoPE ----
    const __bf16* pre = blockIdx.y ? kpre : qpre;
    const float* gvec = blockIdx.y ? gk : gq;
    __bf16* out = blockIdx.y ? Kb : Qb;
    const int s = blockIdx.x;
    float a[3], b[3];
    float ss = 0.f;
#pragma unroll
    for (int j = 0; j < 3; j++) {
        int p = t + 256 * j;
        bf16x2 v = *(const bf16x2*)(pre + (size_t)s * DIM + 2 * p);
        a[j] = (float)v[0]; b[j] = (float)v[1];
        ss += a[j] * a[j] + b[j] * b[j];
    }
    for (int off = 32; off; off >>= 1) ss += __shfl_down(ss, off);
    if ((t & 63) == 0) red[t >> 6] = ss;
    __syncthreads();
    float mean = (red[0] + red[1] + red[2] + red[3]) * (1.f / DIM);
    float rms = rsqrtf(mean + 1e-6f);
    const int fi = s / 640, hi2 = (s % 640) >> 5, wi = s & 31;
#pragma unroll
    for (int j = 0; j < 3; j++) {
        int p = t + 256 * j;
        int c = p & 63;
        int pos = (c < 22) ? fi : ((c < 43) ? hi2 : wi);
        float fc = fcos[pos * 64 + c];
        float fs = fsin[pos * 64 + c];
        float av = a[j] * rms * gvec[2 * p];
        float bv = b[j] * rms * gvec[2 * p + 1];
        float orr = av * fc - bv * fs;
        float oi = av * fs + bv * fc;
        int hh = p >> 6;
        bf16x2 o; o[0] = (__bf16)orr; o[1] = (__bf16)oi;
        *(bf16x2*)(out + ((size_t)hh * SEQ + s) * HD + 2 * c) = o;
    }
}

// ---------------- flash attention, 32 q/wave (2 qg), KV-split x2 -------------
// 3-deep LDS ring (48KB) + counted vmcnt: prefetch distance 2 tiles, raw
// s_barrier (no vmcnt drain), s_waitcnt vmcnt(4) steady state -> the newest
// stage's 4 GLLDs stay in flight across the barrier (T3+T4 pattern).
__global__ __launch_bounds__(256, 3) void attn_split(
    const __bf16* __restrict__ Q, const __bf16* __restrict__ Kk,
    const __bf16* __restrict__ Vp,
    float* __restrict__ pacc,        // [2][NH][SEQ][HD] f32
    float2* __restrict__ pml) {      // [2][NH][SEQ]
    __shared__ __bf16 Ks[3][32 * 128];   // 8KB x3
    __shared__ __bf16 Vs[3][128 * 32];   // 8KB x3 -> 48KB
    const int bid = blockIdx.x;
    const int task = (bid & 7) * 90 + (bid >> 3);   // XCD j owns [90j, 90j+90)
    const int half = task & 1;
    const int hq = task >> 1;                       // 0..359
    const int h = hq / 30;
    const int qb = hq % 30;
    const int t = threadIdx.x;
    const int wv = t >> 6;
    const int lane = t & 63;
    const int lq = lane & 15, g = lane >> 4;
    const int q0 = qb * 128 + wv * 32;
    const int kvbase = half * (SEQ / 2);
    const __bf16* Qh = Q + (size_t)h * SEQ * HD;
    const __bf16* Kh = Kk + (size_t)h * SEQ * HD;
    const __bf16* Vh = Vp + (size_t)h * HD * SEQ;

    bf16x8 qf[2][4];
#pragma unroll
    for (int qg = 0; qg < 2; qg++)
#pragma unroll
        for (int c = 0; c < 4; c++)
            qf[qg][c] = *(const bf16x8*)(Qh + (size_t)(q0 + qg * 16 + lq) * HD + c * 32 + g * 8);

    f32x4 acc[8][2] = {};
    float m[2] = {-1e30f, -1e30f};
    float lp[2] = {0.f, 0.f};

    const int krow0 = wv * 4 + (lane >> 4);
    const int kcb = ((lane & 15) * 16) ^ ((krow0 & 7) << 4);
    const __bf16* kp = Kh + (size_t)(kvbase + krow0) * HD + (kcb >> 1);
    const __bf16* vp = Vh + (size_t)(wv * 16 + (lane >> 2)) * SEQ + kvbase + (lane & 3) * 8;
    auto stage = [&](int i, int b) {
        const __bf16* kpi = kp + (size_t)i * 32 * HD;
        const __bf16* vpi = vp + i * 32;
        GLLD(kpi,           &Ks[b][wv * 512]);
        GLLD(kpi + 16 * HD, &Ks[b][(wv + 4) * 512]);
        GLLD(vpi,            &Vs[b][wv * 512]);
        GLLD(vpi + 64 * SEQ, &Vs[b][(wv + 4) * 512]);
    };

    stage(0, 0);
    stage(1, 1);
    asm volatile("s_waitcnt vmcnt(4)" ::: "memory");   // tile0 landed; tile1 in flight
    __builtin_amdgcn_s_barrier();
    __builtin_amdgcn_sched_barrier(0);

    int c0 = 0, c2 = 2;   // read buf, stage buf
    const int kswz = (lq & 7) << 3;
#pragma unroll 1
    for (int i = 0; i < 60; i++) {
        if (i + 2 < 60) stage(i + 2, c2);   // 2-ahead prefetch, flies under compute
        const __bf16* Kb_ = &Ks[c0][0];
        const __bf16* Vb_ = &Vs[c0][0];

        // ---- QK^T: kf loaded once, feeds both q-groups (LDS reuse x2) ----
        f32x4 sc[2][2] = {};
        __builtin_amdgcn_s_setprio(1);
#pragma unroll
        for (int c = 0; c < 4; c++) {
            int cb = (c * 32 + g * 8) ^ kswz;
            bf16x8 k0 = *(const bf16x8*)(Kb_ + lq * 128 + cb);
            bf16x8 k1 = *(const bf16x8*)(Kb_ + (16 + lq) * 128 + cb);
            sc[0][0] = __builtin_amdgcn_mfma_f32_16x16x32_bf16(k0, qf[0][c], sc[0][0], 0, 0, 0);
            sc[0][1] = __builtin_amdgcn_mfma_f32_16x16x32_bf16(k0, qf[1][c], sc[0][1], 0, 0, 0);
            sc[1][0] = __builtin_amdgcn_mfma_f32_16x16x32_bf16(k1, qf[0][c], sc[1][0], 0, 0, 0);
            sc[1][1] = __builtin_amdgcn_mfma_f32_16x16x32_bf16(k1, qf[1][c], sc[1][1], 0, 0, 0);
        }
        __builtin_amdgcn_s_setprio(0);

        // ---- V fragments early (reused by both q-groups) ----
        bf16x8 vf[8];
#pragma unroll
        for (int dt = 0; dt < 8; dt++)
            vf[dt] = *(const bf16x8*)(Vb_ + (dt * 16 + lq) * 32 + g * 8);

        // ---- softmax per q-group (ballot-gated defer-max; lane-local l) ----
        bf16x8 pa[2];
#pragma unroll
        for (int qg = 0; qg < 2; qg++) {
            float pm = fmaxf(fmaxf(sc[0][qg][0], sc[0][qg][1]), sc[0][qg][2]);
            pm = fmaxf(fmaxf(pm, sc[0][qg][3]), sc[1][qg][0]);
            pm = fmaxf(fmaxf(pm, sc[1][qg][1]), sc[1][qg][2]);
            pm = fmaxf(pm, sc[1][qg][3]);
            if (!__all(pm <= m[qg] + THRRAW)) {
                pm = fmaxf(pm, __shfl_xor(pm, 16));
                pm = fmaxf(pm, __shfl_xor(pm, 32));
                float mn = fmaxf(m[qg], pm);
                float al = __builtin_amdgcn_exp2f(SCL2F * (m[qg] - mn));
                m[qg] = mn; lp[qg] *= al;
#pragma unroll
                for (int dt = 0; dt < 8; dt++)
#pragma unroll
                    for (int r = 0; r < 4; r++) acc[dt][qg][r] *= al;
            }
            float ms = SCL2F * m[qg];
            float p[8], ls = 0.f;
#pragma unroll
            for (int r = 0; r < 4; r++) { p[r] = __builtin_amdgcn_exp2f(SCL2F * sc[0][qg][r] - ms); ls += p[r]; }
#pragma unroll
            for (int r = 0; r < 4; r++) { p[4 + r] = __builtin_amdgcn_exp2f(SCL2F * sc[1][qg][r] - ms); ls += p[4 + r]; }
            lp[qg] += ls;
#pragma unroll
            for (int i2 = 0; i2 < 8; i2++) pa[qg][i2] = (__bf16)p[i2];
        }

        // ---- PV: vf reused across both q-groups ----
        __builtin_amdgcn_s_setprio(1);
#pragma unroll
        for (int dt = 0; dt < 8; dt++) {
            acc[dt][0] = __builtin_amdgcn_mfma_f32_16x16x32_bf16(vf[dt], pa[0], acc[dt][0], 0, 0, 0);
            acc[dt][1] = __builtin_amdgcn_mfma_f32_16x16x32_bf16(vf[dt], pa[1], acc[dt][1], 0, 0, 0);
        }
        __builtin_amdgcn_s_setprio(0);

        // counted wait: newest stage (tile i+2) may stay in flight; everything
        // older (incl. tile i+1, read next iter) is guaranteed complete.
        if (i + 2 < 60) asm volatile("s_waitcnt vmcnt(4)" ::: "memory");
        else            asm volatile("s_waitcnt vmcnt(0)" ::: "memory");
        __builtin_amdgcn_s_barrier();
        __builtin_amdgcn_sched_barrier(0);
        c0 = (c0 == 2) ? 0 : c0 + 1;
        c2 = (c2 == 2) ? 0 : c2 + 1;
    }

    // ---- epilogue: one cross-lane l-reduce per qg, write f32 partials ----
#pragma unroll
    for (int qg = 0; qg < 2; qg++) {
        float lps = lp[qg];
        lps += __shfl_xor(lps, 16);
        lps += __shfl_xor(lps, 32);
        const size_t qrow = (size_t)(half * NHEADS + h) * SEQ + q0 + qg * 16 + lq;
        if (g == 0) pml[qrow] = float2{m[qg], lps};
#pragma unroll
        for (int dt = 0; dt < 8; dt++)
            *(f32x4*)(pacc + qrow * HD + dt * 16 + g * 4) = acc[dt][qg];
    }
}

// ---------------- merge the two kv-half partials -> ob (bf16) ----------------
__global__ __launch_bounds__(256) void attn_merge(
    const float* __restrict__ pacc, const float2* __restrict__ pml,
    __bf16* __restrict__ ob) {
    const int t = threadIdx.x;
    const int qq = blockIdx.x * 8 + (t >> 5);   // 0 .. NH*SEQ-1
    const int d = (t & 31) * 4;
    float2 a = pml[qq], b = pml[NHEADS * SEQ + qq];
    float M = fmaxf(a.x, b.x);
    float w0 = __builtin_amdgcn_exp2f(SCL2F * (a.x - M));
    float w1 = __builtin_amdgcn_exp2f(SCL2F * (b.x - M));
    float den = 1.f / (a.y * w0 + b.y * w1);
    f32x4 n0 = *(const f32x4*)(pacc + (size_t)qq * HD + d);
    f32x4 n1 = *(const f32x4*)(pacc + ((size_t)NHEADS * SEQ + qq) * HD + d);
    int h = qq / SEQ, s = qq % SEQ;
    bf16x4 o;
#pragma unroll
    for (int r = 0; r < 4; r++) o[r] = (__bf16)((n0[r] * w0 + n1[r] * w1) * den);
    *(bf16x4*)(ob + (size_t)s * DIM + h * HD + d) = o;
}

// ---------------- fallback: round-8 single-pass attn ----------------
__global__ __launch_bounds__(256, 4) void attn_single(
    const __bf16* __restrict__ Q, const __bf16* __restrict__ Kk,
    const __bf16* __restrict__ Vp, __bf16* __restrict__ O) {
    __shared__ __bf16 Ks[2][32 * 128];
    __shared__ __bf16 Vs[2][128 * 32];
    const int bid = blockIdx.x;
    const int task = (bid & 7) * 90 + (bid >> 3);
    const int h = task / 60;
    const int qb = task % 60;
    const int t = threadIdx.x;
    const int wv = t >> 6;
    const int lane = t & 63;
    const int lq = lane & 15, g = lane >> 4;
    const int q0 = qb * 64 + wv * 16;
    const __bf16* Qh = Q + (size_t)h * SEQ * HD;
    const __bf16* Kh = Kk + (size_t)h * SEQ * HD;
    const __bf16* Vh = Vp + (size_t)h * HD * SEQ;
    bf16x8 qf[4];
#pragma unroll
    for (int c = 0; c < 4; c++)
        qf[c] = *(const bf16x8*)(Qh + (size_t)(q0 + lq) * HD + c * 32 + g * 8);
    f32x4 acc[8] = {};
    float m = -1e30f, lp = 0.f;
    const int krow_in = lane >> 4;
    const int vrow_in = lane >> 2;
    const int vce = (lane & 3) * 8;
    auto stage = [&](int kv0, int b) {
#pragma unroll
        for (int c = wv; c < 16; c += 4) {
            if (c < 8) {
                int r = c * 4 + krow_in;
                int cb = ((lane & 15) * 16) ^ ((r & 7) << 4);
                GLLD(Kh + (size_t)(kv0 + r) * HD + (cb >> 1), &Ks[b][c * 512]);
            } else {
                int cc = c - 8;
                int rd = cc * 16 + vrow_in;
                GLLD(Vh + (size_t)rd * SEQ + kv0 + vce, &Vs[b][cc * 512]);
            }
        }
    };
    stage(0, 0);
    int buf = 0;
    const int kswz = (lq & 7) << 3;
#pragma unroll 1
    for (int i = 0; i < 120; i++) {
        __syncthreads();
        if (i + 1 < 120) stage((i + 1) * 32, buf ^ 1);
        const __bf16* Kb_ = &Ks[buf][0];
        const __bf16* Vb_ = &Vs[buf][0];
        f32x4 sc0 = {0.f, 0.f, 0.f, 0.f}, sc1 = {0.f, 0.f, 0.f, 0.f};
#pragma unroll
        for (int c = 0; c < 4; c++) {
            int cb = (c * 32 + g * 8) ^ kswz;
            bf16x8 k0 = *(const bf16x8*)(Kb_ + lq * 128 + cb);
            bf16x8 k1 = *(const bf16x8*)(Kb_ + (16 + lq) * 128 + cb);
            sc0 = __builtin_amdgcn_mfma_f32_16x16x32_bf16(k0, qf[c], sc0, 0, 0, 0);
            sc1 = __builtin_amdgcn_mfma_f32_16x16x32_bf16(k1, qf[c], sc1, 0, 0, 0);
        }
        bf16x8 vf[8];
#pragma unroll
        for (int dt = 0; dt < 8; dt++)
            vf[dt] = *(const bf16x8*)(Vb_ + (dt * 16 + lq) * 32 + g * 8);
        float pm = fmaxf(fmaxf(sc0[0], sc0[1]), sc0[2]);
        pm = fmaxf(fmaxf(pm, sc0[3]), sc1[0]);
        pm = fmaxf(fmaxf(pm, sc1[1]), sc1[2]);
        pm = fmaxf(pm, sc1[3]);
        if (!__all(pm <= m + THRRAW)) {
            pm = fmaxf(pm, __shfl_xor(pm, 16));
            pm = fmaxf(pm, __shfl_xor(pm, 32));
            float mn = fmaxf(m, pm);
            float al = __builtin_amdgcn_exp2f(SCL2F * (m - mn));
            m = mn; lp *= al;
#pragma unroll
            for (int dt = 0; dt < 8; dt++)
#pragma unroll
                for (int r = 0; r < 4; r++) acc[dt][r] *= al;
        }
        float ms = SCL2F * m;
        float p[8], ls = 0.f;
#pragma unroll
        for (int r = 0; r < 4; r++) { p[r] = __builtin_amdgcn_exp2f(SCL2F * sc0[r] - ms); ls += p[r]; }
#pragma unroll
        for (int r = 0; r < 4; r++) { p[4 + r] = __builtin_amdgcn_exp2f(SCL2F * sc1[r] - ms); ls += p[4 + r]; }
        lp += ls;
        bf16x8 pa;
#pragma unroll
        for (int i2 = 0; i2 < 8; i2++) pa[i2] = (__bf16)p[i2];
#pragma unroll
        for (int dt = 0; dt < 8; dt++)
            acc[dt] = __builtin_amdgcn_mfma_f32_16x16x32_bf16(vf[dt], pa, acc[dt], 0, 0, 0);
        buf ^= 1;
    }
    float lps = lp;
    lps += __shfl_xor(lps, 16);
    lps += __shfl_xor(lps, 32);
    float inv = 1.f / lps;
#pragma unroll
    for (int dt = 0; dt < 8; dt++) {
        bf16x4 o;
#pragma unroll
        for (int r = 0; r < 4; r++) o[r] = (__bf16)(acc[dt][r] * inv);
        *(bf16x4*)(O + (size_t)(q0 + lq) * DIM + h * HD + dt * 16 + g * 4) = o;
    }
}

extern "C" void kernel_launch(void* const* d_in, const int* in_sizes, int n_in,
                              void* d_out, int out_size, void* d_ws, size_t ws_size,
                              hipStream_t stream) {
    const float* x = (const float*)d_in[0];
    const float* Wq = (const float*)d_in[1];
    const float* bq = (const float*)d_in[2];
    const float* Wk = (const float*)d_in[3];
    const float* bk = (const float*)d_in[4];
    const float* Wv = (const float*)d_in[5];
    const float* bv = (const float*)d_in[6];
    const float* Wo = (const float*)d_in[7];
    const float* bo = (const float*)d_in[8];
    const float* gq = (const float*)d_in[9];
    const float* gk = (const float*)d_in[10];
    const float* fcos = (const float*)d_in[11];
    const float* fsin = (const float*)d_in[12];
    float* out = (float*)d_out;

    char* p = (char*)d_ws;
    const size_t SZ_SD = (size_t)SEQ * DIM * 2;   // 11.25 MB
    const size_t SZ_W = (size_t)DIM * DIM * 2;    // 4.5 MB
    __bf16* xb   = (__bf16*)p;  p += SZ_SD;   // reused as Qb after QKV GEMM
    __bf16* Wob  = (__bf16*)p;  p += SZ_W;    // live till out-proj
    __bf16* Wqb  = (__bf16*)p;  p += SZ_W;    // ┐ dead after QKV GEMM/norm;
    __bf16* Wkb  = (__bf16*)p;  p += SZ_W;    // │ overlaid by pacc f32
    __bf16* Wvb  = (__bf16*)p;  p += SZ_W;    // │ (47.19 MB <= 49.5 MB)
    __bf16* qpre = (__bf16*)p;  p += SZ_SD;   // │ during attn_split
    __bf16* kpre = (__bf16*)p;  p += SZ_SD;   // │
    __bf16* vpre = (__bf16*)p;  p += SZ_SD;   // ┘
    __bf16* Kb   = (__bf16*)p;  p += SZ_SD;
    __bf16* Vtb  = (__bf16*)p;  p += SZ_SD;
    float2* pml  = (float2*)p;  p += sizeof(float2) * 2 * NHEADS * SEQ;
    float* pacc = (float*)Wqb;                // overlay
    __bf16* Qb = xb;
    const bool split_ok = ws_size >= (size_t)(p - (char*)d_ws);

    const int n4_x = SEQ * DIM / 4;
    const int n4_w = DIM * DIM / 4;
    cvt_bf16_5<<<dim3((n4_x + 255) / 256, 5), 256, 0, stream>>>(
        x, Wq, Wk, Wv, Wo, xb, Wqb, Wkb, Wvb, Wob, n4_x, n4_w);

    gemm256<0><<<dim3(540), 256, 0, stream>>>(
        xb, Wqb, Wkb, Wvb, bq, bk, bv, qpre, kpre, vpre, DIM, DIM);

    norm_tr<<<dim3(SEQ, 3), 256, 0, stream>>>(
        qpre, kpre, gq, gk, fcos, fsin, Qb, Kb, vpre, Vtb);

    if (split_ok) {
        __bf16* ob = Kb;   // Kb dead after attn_split
        attn_split<<<dim3(720), 256, 0, stream>>>(Qb, Kb, Vtb, pacc, pml);
        attn_merge<<<dim3(NHEADS * SEQ / 8), 256, 0, stream>>>(pacc, pml, ob);
        gemm256<1><<<dim3(180), 256, 0, stream>>>(
            ob, Wob, Wob, Wob, bo, bo, bo, out, out, out, DIM, DIM);
    } else {
        __bf16* ob = qpre;
        attn_single<<<dim3(720), 256, 0, stream>>>(Qb, Kb, Vtb, ob);
        gemm256<1><<<dim3(180), 256, 0, stream>>>(
            ob, Wob, Wob, Wob, bo, bo, bo, out, out, out, DIM, DIM);
    }
}

// Round 13
// 264.243 us; speedup vs baseline: 1.0191x; 1.0191x over previous
//
#include <hip/hip_runtime.h>
#include <hip/hip_bf16.h>
#include <cstdint>

#define DIM 1536
#define NHEADS 12
#define HD 128
#define SEQ 3840
#define SCL2F 0.1275365308119098f   /* (1/sqrt(128)) * log2(e) */
#define THRRAW 90.50966799187809f   /* 8 nats / (1/sqrt(128))  */

typedef float f32x4 __attribute__((ext_vector_type(4)));
typedef __bf16 bf16x8 __attribute__((ext_vector_type(8)));
typedef __bf16 bf16x4 __attribute__((ext_vector_type(4)));
typedef __bf16 bf16x2 __attribute__((ext_vector_type(2)));
typedef unsigned int u32;
typedef u32 u32x4 __attribute__((ext_vector_type(4)));

#define GLLD(g, l) __builtin_amdgcn_global_load_lds( \
    (const __attribute__((address_space(1))) void*)(g), \
    (__attribute__((address_space(3))) void*)(l), 16, 0, 0)

// ---------------- fp32 -> bf16 convert, 5 tensors in one launch ----------------
__global__ __launch_bounds__(256) void cvt_bf16_5(
    const float* __restrict__ s0, const float* __restrict__ s1, const float* __restrict__ s2,
    const float* __restrict__ s3, const float* __restrict__ s4,
    __bf16* __restrict__ d0, __bf16* __restrict__ d1, __bf16* __restrict__ d2,
    __bf16* __restrict__ d3, __bf16* __restrict__ d4,
    int n4_0, int n4_w) {
    const float* src; __bf16* dst; int n4;
    switch (blockIdx.y) {
        case 0: src = s0; dst = d0; n4 = n4_0; break;
        case 1: src = s1; dst = d1; n4 = n4_w; break;
        case 2: src = s2; dst = d2; n4 = n4_w; break;
        case 3: src = s3; dst = d3; n4 = n4_w; break;
        default: src = s4; dst = d4; n4 = n4_w; break;
    }
    int i = blockIdx.x * 256 + threadIdx.x;
    if (i < n4) {
        f32x4 v = ((const f32x4*)src)[i];
        bf16x4 o;
        o[0] = (__bf16)v[0]; o[1] = (__bf16)v[1];
        o[2] = (__bf16)v[2]; o[3] = (__bf16)v[3];
        ((bf16x4*)dst)[i] = o;
    }
}

// ---------------- GEMM 256x128, BK=32, triple-buffer, counted vmcnt ----------
template <int OUTF32>
__global__ __launch_bounds__(256, 2) void gemm256(
    const __bf16* __restrict__ A,
    const __bf16* __restrict__ B0, const __bf16* __restrict__ B1, const __bf16* __restrict__ B2,
    const float* __restrict__ bias0, const float* __restrict__ bias1, const float* __restrict__ bias2,
    void* __restrict__ C0v, void* __restrict__ C1v, void* __restrict__ C2v,
    int N, int K) {
    // --- XCD-bijective remap (nwg % 8 may be != 0) ---
    const int orig = blockIdx.x;
    const int nwg = gridDim.x;
    const int qq_ = nwg >> 3, rr_ = nwg & 7;
    const int xcd = orig & 7, off = orig >> 3;
    const int wgid = (xcd < rr_ ? xcd * (qq_ + 1) : rr_ * (qq_ + 1) + (xcd - rr_) * qq_) + off;
    const int z = wgid / 180;
    const int rem = wgid - z * 180;
    const int by = rem / 12;       // m-block (y-major: same-A blocks contiguous)
    const int bx = rem - by * 12;  // n-block

    const __bf16* B = B0; const float* bias = bias0; void* Cv = C0v;
    if (z == 1) { B = B1; bias = bias1; Cv = C1v; }
    else if (z == 2) { B = B2; bias = bias2; Cv = C2v; }

    __shared__ __bf16 sA[3][256 * 32];   // 16KB x3
    __shared__ __bf16 sB[3][128 * 32];   // 8KB x3  -> 72KB total

    const int t = threadIdx.x;
    const int wid = t >> 6, lane = t & 63;
    const int lr = lane & 15, lg = lane >> 4;
    const int wr = (wid >> 1) * 128, wc = (wid & 1) * 64;

    const __bf16* pa = A + ((long long)by * 256 + (t >> 2)) * K + (t & 3) * 8;
    const __bf16* pb = B + ((long long)bx * 128 + (t >> 2)) * K + (t & 3) * 8;
    const int ldsbase = wid * 512;

    auto stage = [&](int kk, int bufi) {
#pragma unroll
        for (int r = 0; r < 4; r++)
            GLLD(pa + (long long)(r * 64) * K + kk, &sA[bufi][r * 2048 + ldsbase]);
#pragma unroll
        for (int r = 0; r < 2; r++)
            GLLD(pb + (long long)(r * 64) * K + kk, &sB[bufi][r * 2048 + ldsbase]);
    };

    f32x4 acc[8][4] = {};
    const int NT = K / 32;

    stage(0, 0);
    stage(32, 1);
    asm volatile("s_waitcnt vmcnt(6)" ::: "memory");
    __builtin_amdgcn_s_barrier();
    __builtin_amdgcn_sched_barrier(0);

    int c0 = 0, c2 = 2;
#pragma unroll 1
    for (int i = 0; i < NT; i++) {
        const __bf16* sAc = &sA[0][0] + c0 * (256 * 32);
        const __bf16* sBc = &sB[0][0] + c0 * (128 * 32);
        bf16x8 af[8], bfr[4];
#pragma unroll
        for (int mI = 0; mI < 8; mI++)
            af[mI] = *(const bf16x8*)(sAc + (wr + mI * 16 + lr) * 32 + lg * 8);
#pragma unroll
        for (int nI = 0; nI < 4; nI++)
            bfr[nI] = *(const bf16x8*)(sBc + (wc + nI * 16 + lr) * 32 + lg * 8);
        if (i + 2 < NT) stage((i + 2) * 32, c2);

        __builtin_amdgcn_s_setprio(1);
#pragma unroll
        for (int mI = 0; mI < 8; mI++) {
            acc[mI][0] = __builtin_amdgcn_mfma_f32_16x16x32_bf16(af[mI], bfr[0], acc[mI][0], 0, 0, 0);
            acc[mI][1] = __builtin_amdgcn_mfma_f32_16x16x32_bf16(af[mI], bfr[1], acc[mI][1], 0, 0, 0);
        }
        __builtin_amdgcn_s_setprio(0);
        __builtin_amdgcn_s_barrier();
        __builtin_amdgcn_s_setprio(1);
#pragma unroll
        for (int mI = 0; mI < 8; mI++) {
            acc[mI][2] = __builtin_amdgcn_mfma_f32_16x16x32_bf16(af[mI], bfr[2], acc[mI][2], 0, 0, 0);
            acc[mI][3] = __builtin_amdgcn_mfma_f32_16x16x32_bf16(af[mI], bfr[3], acc[mI][3], 0, 0, 0);
        }
        __builtin_amdgcn_s_setprio(0);

        if (i + 2 < NT) asm volatile("s_waitcnt vmcnt(6)" ::: "memory");
        else            asm volatile("s_waitcnt vmcnt(0)" ::: "memory");
        __builtin_amdgcn_s_barrier();
        __builtin_amdgcn_sched_barrier(0);
        c0 = (c0 == 2) ? 0 : c0 + 1;
        c2 = (c2 == 2) ? 0 : c2 + 1;
    }

    const int cb = bx * 128 + wc;
    const int rb_ = by * 256 + wr;
#pragma unroll
    for (int nI = 0; nI < 4; nI++) {
        int col = cb + nI * 16 + lr;
        float bv = bias[col];
#pragma unroll
        for (int mI = 0; mI < 8; mI++) {
            int row0 = rb_ + mI * 16 + lg * 4;
#pragma unroll
            for (int r = 0; r < 4; r++) {
                float v = acc[mI][nI][r] + bv;
                if (OUTF32) ((float*)Cv)[(long long)(row0 + r) * N + col] = v;
                else ((__bf16*)Cv)[(long long)(row0 + r) * N + col] = (__bf16)v;
            }
        }
    }
}

// ------ fused post-QKV pass: y=0 norm(q), y=1 norm(k), y=2 V-transpose -------
__global__ __launch_bounds__(256) void norm_tr(
    const __bf16* __restrict__ qpre, const __bf16* __restrict__ kpre,
    const float* __restrict__ gq, const float* __restrict__ gk,
    const float* __restrict__ fcos, const float* __restrict__ fsin,
    __bf16* __restrict__ Qb, __bf16* __restrict__ Kb,
    const __bf16* __restrict__ vpre, __bf16* __restrict__ Vtb) {
    __shared__ __bf16 tile[64][68];
    __shared__ float red[4];
    const int t = threadIdx.x;

    if (blockIdx.y == 2) {
        // ---- transpose [SEQ][DIM] -> [DIM][SEQ] with kv-slot permute ----
        const int bxx = blockIdx.x;
        if (bxx >= (SEQ / 64) * (DIM / 64)) return;
        const int sb = (bxx % (SEQ / 64)) * 64, cb = (bxx / (SEQ / 64)) * 64;
        const int tx = t & 15, ty = t >> 4;
#pragma unroll
        for (int i = 0; i < 4; i++) {
            int r = ty + i * 16;
            bf16x4 v = *(const bf16x4*)(vpre + (size_t)(sb + r) * DIM + cb + tx * 4);
            *(bf16x4*)&tile[r][tx * 4] = v;
        }
        __syncthreads();
        int s0 = sb + tx * 4;
        int j = (s0 >> 2) & 7;
        int u = (j < 4) ? (j << 1) : ((j << 1) - 7);
        int sp = (s0 & ~31) + (u << 2);
#pragma unroll
        for (int i = 0; i < 4; i++) {
            int c = ty + i * 16;
            bf16x4 v;
            v[0] = tile[tx * 4 + 0][c]; v[1] = tile[tx * 4 + 1][c];
            v[2] = tile[tx * 4 + 2][c]; v[3] = tile[tx * 4 + 3][c];
            *(bf16x4*)(Vtb + (size_t)(cb + c) * SEQ + sp) = v;
        }
        return;
    }

    // ---- RMSNorm + RoPE ----
    const __bf16* pre = blockIdx.y ? kpre : qpre;
    const float* gvec = blockIdx.y ? gk : gq;
    __bf16* out = blockIdx.y ? Kb : Qb;
    const int s = blockIdx.x;
    float a[3], b[3];
    float ss = 0.f;
#pragma unroll
    for (int j = 0; j < 3; j++) {
        int p = t + 256 * j;
        bf16x2 v = *(const bf16x2*)(pre + (size_t)s * DIM + 2 * p);
        a[j] = (float)v[0]; b[j] = (float)v[1];
        ss += a[j] * a[j] + b[j] * b[j];
    }
    for (int off = 32; off; off >>= 1) ss += __shfl_down(ss, off);
    if ((t & 63) == 0) red[t >> 6] = ss;
    __syncthreads();
    float mean = (red[0] + red[1] + red[2] + red[3]) * (1.f / DIM);
    float rms = rsqrtf(mean + 1e-6f);
    const int fi = s / 640, hi2 = (s % 640) >> 5, wi = s & 31;
#pragma unroll
    for (int j = 0; j < 3; j++) {
        int p = t + 256 * j;
        int c = p & 63;
        int pos = (c < 22) ? fi : ((c < 43) ? hi2 : wi);
        float fc = fcos[pos * 64 + c];
        float fs = fsin[pos * 64 + c];
        float av = a[j] * rms * gvec[2 * p];
        float bv = b[j] * rms * gvec[2 * p + 1];
        float orr = av * fc - bv * fs;
        float oi = av * fs + bv * fc;
        int hh = p >> 6;
        bf16x2 o; o[0] = (__bf16)orr; o[1] = (__bf16)oi;
        *(bf16x2*)(out + ((size_t)hh * SEQ + s) * HD + 2 * c) = o;
    }
}

// ---------------- flash attention, 32 q/wave (2 qg), KV-split x2 -------------
// Round-11 body (2-buffer, __syncthreads): measured best at 113.6 µs.
// (3-buffer counted-vmcnt variant regressed to 123.5 µs in round 12 —
// compiler's implicit scheduling + multi-block overlap already covers the
// staging latency; sched_barrier pinning hurt.)
__global__ __launch_bounds__(256, 3) void attn_split(
    const __bf16* __restrict__ Q, const __bf16* __restrict__ Kk,
    const __bf16* __restrict__ Vp,
    float* __restrict__ pacc,        // [2][NH][SEQ][HD] f32
    float2* __restrict__ pml) {      // [2][NH][SEQ]
    __shared__ __bf16 Ks[2][32 * 128];   // 8KB x2
    __shared__ __bf16 Vs[2][128 * 32];   // 8KB x2
    const int bid = blockIdx.x;
    const int task = (bid & 7) * 90 + (bid >> 3);   // XCD j owns [90j, 90j+90)
    const int half = task & 1;
    const int hq = task >> 1;                       // 0..359
    const int h = hq / 30;
    const int qb = hq % 30;
    const int t = threadIdx.x;
    const int wv = t >> 6;
    const int lane = t & 63;
    const int lq = lane & 15, g = lane >> 4;
    const int q0 = qb * 128 + wv * 32;
    const int kvbase = half * (SEQ / 2);
    const __bf16* Qh = Q + (size_t)h * SEQ * HD;
    const __bf16* Kh = Kk + (size_t)h * SEQ * HD;
    const __bf16* Vh = Vp + (size_t)h * HD * SEQ;

    bf16x8 qf[2][4];
#pragma unroll
    for (int qg = 0; qg < 2; qg++)
#pragma unroll
        for (int c = 0; c < 4; c++)
            qf[qg][c] = *(const bf16x8*)(Qh + (size_t)(q0 + qg * 16 + lq) * HD + c * 32 + g * 8);

    f32x4 acc[8][2] = {};
    float m[2] = {-1e30f, -1e30f};
    float lp[2] = {0.f, 0.f};

    const int krow0 = wv * 4 + (lane >> 4);
    const int kcb = ((lane & 15) * 16) ^ ((krow0 & 7) << 4);
    const __bf16* kp = Kh + (size_t)(kvbase + krow0) * HD + (kcb >> 1);
    const __bf16* vp = Vh + (size_t)(wv * 16 + (lane >> 2)) * SEQ + kvbase + (lane & 3) * 8;
    auto stage = [&](int i, int b) {
        const __bf16* kpi = kp + (size_t)i * 32 * HD;
        const __bf16* vpi = vp + i * 32;
        GLLD(kpi,           &Ks[b][wv * 512]);
        GLLD(kpi + 16 * HD, &Ks[b][(wv + 4) * 512]);
        GLLD(vpi,            &Vs[b][wv * 512]);
        GLLD(vpi + 64 * SEQ, &Vs[b][(wv + 4) * 512]);
    };

    stage(0, 0);
    int buf = 0;
    const int kswz = (lq & 7) << 3;
#pragma unroll 1
    for (int i = 0; i < 60; i++) {
        __syncthreads();
        if (i + 1 < 60) stage(i + 1, buf ^ 1);
        const __bf16* Kb_ = &Ks[buf][0];
        const __bf16* Vb_ = &Vs[buf][0];

        // ---- QK^T: kf loaded once, feeds both q-groups (LDS reuse x2) ----
        f32x4 sc[2][2] = {};
        __builtin_amdgcn_s_setprio(1);
#pragma unroll
        for (int c = 0; c < 4; c++) {
            int cb = (c * 32 + g * 8) ^ kswz;
            bf16x8 k0 = *(const bf16x8*)(Kb_ + lq * 128 + cb);
            bf16x8 k1 = *(const bf16x8*)(Kb_ + (16 + lq) * 128 + cb);
            sc[0][0] = __builtin_amdgcn_mfma_f32_16x16x32_bf16(k0, qf[0][c], sc[0][0], 0, 0, 0);
            sc[0][1] = __builtin_amdgcn_mfma_f32_16x16x32_bf16(k0, qf[1][c], sc[0][1], 0, 0, 0);
            sc[1][0] = __builtin_amdgcn_mfma_f32_16x16x32_bf16(k1, qf[0][c], sc[1][0], 0, 0, 0);
            sc[1][1] = __builtin_amdgcn_mfma_f32_16x16x32_bf16(k1, qf[1][c], sc[1][1], 0, 0, 0);
        }
        __builtin_amdgcn_s_setprio(0);

        // ---- V fragments early (reused by both q-groups) ----
        bf16x8 vf[8];
#pragma unroll
        for (int dt = 0; dt < 8; dt++)
            vf[dt] = *(const bf16x8*)(Vb_ + (dt * 16 + lq) * 32 + g * 8);

        // ---- softmax per q-group (ballot-gated defer-max; lane-local l) ----
        bf16x8 pa[2];
#pragma unroll
        for (int qg = 0; qg < 2; qg++) {
            float pm = fmaxf(fmaxf(sc[0][qg][0], sc[0][qg][1]), sc[0][qg][2]);
            pm = fmaxf(fmaxf(pm, sc[0][qg][3]), sc[1][qg][0]);
            pm = fmaxf(fmaxf(pm, sc[1][qg][1]), sc[1][qg][2]);
            pm = fmaxf(pm, sc[1][qg][3]);
            if (!__all(pm <= m[qg] + THRRAW)) {
                pm = fmaxf(pm, __shfl_xor(pm, 16));
                pm = fmaxf(pm, __shfl_xor(pm, 32));
                float mn = fmaxf(m[qg], pm);
                float al = __builtin_amdgcn_exp2f(SCL2F * (m[qg] - mn));
                m[qg] = mn; lp[qg] *= al;
#pragma unroll
                for (int dt = 0; dt < 8; dt++)
#pragma unroll
                    for (int r = 0; r < 4; r++) acc[dt][qg][r] *= al;
            }
            float ms = SCL2F * m[qg];
            float p[8], ls = 0.f;
#pragma unroll
            for (int r = 0; r < 4; r++) { p[r] = __builtin_amdgcn_exp2f(SCL2F * sc[0][qg][r] - ms); ls += p[r]; }
#pragma unroll
            for (int r = 0; r < 4; r++) { p[4 + r] = __builtin_amdgcn_exp2f(SCL2F * sc[1][qg][r] - ms); ls += p[4 + r]; }
            lp[qg] += ls;
#pragma unroll
            for (int i2 = 0; i2 < 8; i2++) pa[qg][i2] = (__bf16)p[i2];
        }

        // ---- PV: vf reused across both q-groups ----
        __builtin_amdgcn_s_setprio(1);
#pragma unroll
        for (int dt = 0; dt < 8; dt++) {
            acc[dt][0] = __builtin_amdgcn_mfma_f32_16x16x32_bf16(vf[dt], pa[0], acc[dt][0], 0, 0, 0);
            acc[dt][1] = __builtin_amdgcn_mfma_f32_16x16x32_bf16(vf[dt], pa[1], acc[dt][1], 0, 0, 0);
        }
        __builtin_amdgcn_s_setprio(0);
        buf ^= 1;
    }

    // ---- epilogue: one cross-lane l-reduce per qg, write f32 partials ----
#pragma unroll
    for (int qg = 0; qg < 2; qg++) {
        float lps = lp[qg];
        lps += __shfl_xor(lps, 16);
        lps += __shfl_xor(lps, 32);
        const size_t qrow = (size_t)(half * NHEADS + h) * SEQ + q0 + qg * 16 + lq;
        if (g == 0) pml[qrow] = float2{m[qg], lps};
#pragma unroll
        for (int dt = 0; dt < 8; dt++)
            *(f32x4*)(pacc + qrow * HD + dt * 16 + g * 4) = acc[dt][qg];
    }
}

// ---------------- merge the two kv-half partials -> ob (bf16) ----------------
__global__ __launch_bounds__(256) void attn_merge(
    const float* __restrict__ pacc, const float2* __restrict__ pml,
    __bf16* __restrict__ ob) {
    const int t = threadIdx.x;
    const int qq = blockIdx.x * 8 + (t >> 5);   // 0 .. NH*SEQ-1
    const int d = (t & 31) * 4;
    float2 a = pml[qq], b = pml[NHEADS * SEQ + qq];
    float M = fmaxf(a.x, b.x);
    float w0 = __builtin_amdgcn_exp2f(SCL2F * (a.x - M));
    float w1 = __builtin_amdgcn_exp2f(SCL2F * (b.x - M));
    float den = 1.f / (a.y * w0 + b.y * w1);
    f32x4 n0 = *(const f32x4*)(pacc + (size_t)qq * HD + d);
    f32x4 n1 = *(const f32x4*)(pacc + ((size_t)NHEADS * SEQ + qq) * HD + d);
    int h = qq / SEQ, s = qq % SEQ;
    bf16x4 o;
#pragma unroll
    for (int r = 0; r < 4; r++) o[r] = (__bf16)((n0[r] * w0 + n1[r] * w1) * den);
    *(bf16x4*)(ob + (size_t)s * DIM + h * HD + d) = o;
}

// ---------------- fallback: round-8 single-pass attn ----------------
__global__ __launch_bounds__(256, 4) void attn_single(
    const __bf16* __restrict__ Q, const __bf16* __restrict__ Kk,
    const __bf16* __restrict__ Vp, __bf16* __restrict__ O) {
    __shared__ __bf16 Ks[2][32 * 128];
    __shared__ __bf16 Vs[2][128 * 32];
    const int bid = blockIdx.x;
    const int task = (bid & 7) * 90 + (bid >> 3);
    const int h = task / 60;
    const int qb = task % 60;
    const int t = threadIdx.x;
    const int wv = t >> 6;
    const int lane = t & 63;
    const int lq = lane & 15, g = lane >> 4;
    const int q0 = qb * 64 + wv * 16;
    const __bf16* Qh = Q + (size_t)h * SEQ * HD;
    const __bf16* Kh = Kk + (size_t)h * SEQ * HD;
    const __bf16* Vh = Vp + (size_t)h * HD * SEQ;
    bf16x8 qf[4];
#pragma unroll
    for (int c = 0; c < 4; c++)
        qf[c] = *(const bf16x8*)(Qh + (size_t)(q0 + lq) * HD + c * 32 + g * 8);
    f32x4 acc[8] = {};
    float m = -1e30f, lp = 0.f;
    const int krow_in = lane >> 4;
    const int vrow_in = lane >> 2;
    const int vce = (lane & 3) * 8;
    auto stage = [&](int kv0, int b) {
#pragma unroll
        for (int c = wv; c < 16; c += 4) {
            if (c < 8) {
                int r = c * 4 + krow_in;
                int cb = ((lane & 15) * 16) ^ ((r & 7) << 4);
                GLLD(Kh + (size_t)(kv0 + r) * HD + (cb >> 1), &Ks[b][c * 512]);
            } else {
                int cc = c - 8;
                int rd = cc * 16 + vrow_in;
                GLLD(Vh + (size_t)rd * SEQ + kv0 + vce, &Vs[b][cc * 512]);
            }
        }
    };
    stage(0, 0);
    int buf = 0;
    const int kswz = (lq & 7) << 3;
#pragma unroll 1
    for (int i = 0; i < 120; i++) {
        __syncthreads();
        if (i + 1 < 120) stage((i + 1) * 32, buf ^ 1);
        const __bf16* Kb_ = &Ks[buf][0];
        const __bf16* Vb_ = &Vs[buf][0];
        f32x4 sc0 = {0.f, 0.f, 0.f, 0.f}, sc1 = {0.f, 0.f, 0.f, 0.f};
#pragma unroll
        for (int c = 0; c < 4; c++) {
            int cb = (c * 32 + g * 8) ^ kswz;
            bf16x8 k0 = *(const bf16x8*)(Kb_ + lq * 128 + cb);
            bf16x8 k1 = *(const bf16x8*)(Kb_ + (16 + lq) * 128 + cb);
            sc0 = __builtin_amdgcn_mfma_f32_16x16x32_bf16(k0, qf[c], sc0, 0, 0, 0);
            sc1 = __builtin_amdgcn_mfma_f32_16x16x32_bf16(k1, qf[c], sc1, 0, 0, 0);
        }
        bf16x8 vf[8];
#pragma unroll
        for (int dt = 0; dt < 8; dt++)
            vf[dt] = *(const bf16x8*)(Vb_ + (dt * 16 + lq) * 32 + g * 8);
        float pm = fmaxf(fmaxf(sc0[0], sc0[1]), sc0[2]);
        pm = fmaxf(fmaxf(pm, sc0[3]), sc1[0]);
        pm = fmaxf(fmaxf(pm, sc1[1]), sc1[2]);
        pm = fmaxf(pm, sc1[3]);
        if (!__all(pm <= m + THRRAW)) {
            pm = fmaxf(pm, __shfl_xor(pm, 16));
            pm = fmaxf(pm, __shfl_xor(pm, 32));
            float mn = fmaxf(m, pm);
            float al = __builtin_amdgcn_exp2f(SCL2F * (m - mn));
            m = mn; lp *= al;
#pragma unroll
            for (int dt = 0; dt < 8; dt++)
#pragma unroll
                for (int r = 0; r < 4; r++) acc[dt][r] *= al;
        }
        float ms = SCL2F * m;
        float p[8], ls = 0.f;
#pragma unroll
        for (int r = 0; r < 4; r++) { p[r] = __builtin_amdgcn_exp2f(SCL2F * sc0[r] - ms); ls += p[r]; }
#pragma unroll
        for (int r = 0; r < 4; r++) { p[4 + r] = __builtin_amdgcn_exp2f(SCL2F * sc1[r] - ms); ls += p[4 + r]; }
        lp += ls;
        bf16x8 pa;
#pragma unroll
        for (int i2 = 0; i2 < 8; i2++) pa[i2] = (__bf16)p[i2];
#pragma unroll
        for (int dt = 0; dt < 8; dt++)
            acc[dt] = __builtin_amdgcn_mfma_f32_16x16x32_bf16(vf[dt], pa, acc[dt], 0, 0, 0);
        buf ^= 1;
    }
    float lps = lp;
    lps += __shfl_xor(lps, 16);
    lps += __shfl_xor(lps, 32);
    float inv = 1.f / lps;
#pragma unroll
    for (int dt = 0; dt < 8; dt++) {
        bf16x4 o;
#pragma unroll
        for (int r = 0; r < 4; r++) o[r] = (__bf16)(acc[dt][r] * inv);
        *(bf16x4*)(O + (size_t)(q0 + lq) * DIM + h * HD + dt * 16 + g * 4) = o;
    }
}

extern "C" void kernel_launch(void* const* d_in, const int* in_sizes, int n_in,
                              void* d_out, int out_size, void* d_ws, size_t ws_size,
                              hipStream_t stream) {
    const float* x = (const float*)d_in[0];
    const float* Wq = (const float*)d_in[1];
    const float* bq = (const float*)d_in[2];
    const float* Wk = (const float*)d_in[3];
    const float* bk = (const float*)d_in[4];
    const float* Wv = (const float*)d_in[5];
    const float* bv = (const float*)d_in[6];
    const float* Wo = (const float*)d_in[7];
    const float* bo = (const float*)d_in[8];
    const float* gq = (const float*)d_in[9];
    const float* gk = (const float*)d_in[10];
    const float* fcos = (const float*)d_in[11];
    const float* fsin = (const float*)d_in[12];
    float* out = (float*)d_out;

    char* p = (char*)d_ws;
    const size_t SZ_SD = (size_t)SEQ * DIM * 2;   // 11.25 MB
    const size_t SZ_W = (size_t)DIM * DIM * 2;    // 4.5 MB
    __bf16* xb   = (__bf16*)p;  p += SZ_SD;   // reused as Qb after QKV GEMM
    __bf16* Wob  = (__bf16*)p;  p += SZ_W;    // live till out-proj
    __bf16* Wqb  = (__bf16*)p;  p += SZ_W;    // ┐ dead after QKV GEMM/norm;
    __bf16* Wkb  = (__bf16*)p;  p += SZ_W;    // │ overlaid by pacc f32
    __bf16* Wvb  = (__bf16*)p;  p += SZ_W;    // │ (47.19 MB <= 49.5 MB)
    __bf16* qpre = (__bf16*)p;  p += SZ_SD;   // │ during attn_split
    __bf16* kpre = (__bf16*)p;  p += SZ_SD;   // │
    __bf16* vpre = (__bf16*)p;  p += SZ_SD;   // ┘
    __bf16* Kb   = (__bf16*)p;  p += SZ_SD;
    __bf16* Vtb  = (__bf16*)p;  p += SZ_SD;
    float2* pml  = (float2*)p;  p += sizeof(float2) * 2 * NHEADS * SEQ;
    float* pacc = (float*)Wqb;                // overlay
    __bf16* Qb = xb;
    const bool split_ok = ws_size >= (size_t)(p - (char*)d_ws);

    const int n4_x = SEQ * DIM / 4;
    const int n4_w = DIM * DIM / 4;
    cvt_bf16_5<<<dim3((n4_x + 255) / 256, 5), 256, 0, stream>>>(
        x, Wq, Wk, Wv, Wo, xb, Wqb, Wkb, Wvb, Wob, n4_x, n4_w);

    gemm256<0><<<dim3(540), 256, 0, stream>>>(
        xb, Wqb, Wkb, Wvb, bq, bk, bv, qpre, kpre, vpre, DIM, DIM);

    norm_tr<<<dim3(SEQ, 3), 256, 0, stream>>>(
        qpre, kpre, gq, gk, fcos, fsin, Qb, Kb, vpre, Vtb);

    if (split_ok) {
        __bf16* ob = Kb;   // Kb dead after attn_split
        attn_split<<<dim3(720), 256, 0, stream>>>(Qb, Kb, Vtb, pacc, pml);
        attn_merge<<<dim3(NHEADS * SEQ / 8), 256, 0, stream>>>(pacc, pml, ob);
        gemm256<1><<<dim3(180), 256, 0, stream>>>(
            ob, Wob, Wob, Wob, bo, bo, bo, out, out, out, DIM, DIM);
    } else {
        __bf16* ob = qpre;
        attn_single<<<dim3(720), 256, 0, stream>>>(Qb, Kb, Vtb, ob);
        gemm256<1><<<dim3(180), 256, 0, stream>>>(
            ob, Wob, Wob, Wob, bo, bo, bo, out, out, out, DIM, DIM);
    }
}